// Round 20
// baseline (45.764 us; speedup 1.0000x reference)
//
#include <hip/hip_runtime.h>
#include <hip/hip_bf16.h>

#define NN 8192
#define KK 256
#define HN 4096
#define TM 256
#define TN 128
#define BK 128  // fp8 bytes per LDS row (128 B rows = verified swizzle)
#define NBLK 1056  // lower-triangle 256x128 tiles: 8*132, bijective XCD swizzle

typedef __attribute__((ext_vector_type(4))) float f32x4;
typedef __attribute__((ext_vector_type(4))) int i32x4;

__device__ __forceinline__ void gload_lds16(const void* g, void* l) {
  __builtin_amdgcn_global_load_lds(
      (const __attribute__((address_space(1))) unsigned int*)g,
      (__attribute__((address_space(3))) unsigned int*)l, 16, 0, 0);
}

// ---- Kernel 1: row-normalize z (f32) -> fp8 e4m3 zn (K-PERMUTED layout);
// block 0 zeroes out. Within each 128-byte half-row (kt), original
// k = kk*32 + q*8 + j is stored at p = q*32 + kk*8 + j. Gram dot-products
// are invariant since both operands share the same K-permutation.
__global__ void nrm_kernel(const float* __restrict__ z,
                           unsigned int* __restrict__ zn,
                           float* __restrict__ out) {
  if (blockIdx.x == 0 && threadIdx.x == 0) out[0] = 0.0f;
  int row = (blockIdx.x << 2) + (threadIdx.x >> 6);
  int lane = threadIdx.x & 63;
  float4 v = ((const float4*)(z + (size_t)row * KK))[lane];
  float ss = v.x * v.x + v.y * v.y + v.z * v.z + v.w * v.w;
#pragma unroll
  for (int off = 32; off; off >>= 1) ss += __shfl_xor(ss, off, 64);
  float scale = 1.0f / fmaxf(sqrtf(ss), 1e-8f);
  int lo = __builtin_amdgcn_cvt_pk_fp8_f32(v.x * scale, v.y * scale, 0, false);
  int all = __builtin_amdgcn_cvt_pk_fp8_f32(v.z * scale, v.w * scale, lo, true);
  // lane covers k = 4*lane..+3. Bits: kt=b5, kk=(b4b3), q=(b2b1), half=b0.
  // permuted dword = kt*32 + q*8 + kk*2 + b0  (bit permutation: bijective)
  int dw = ((lane >> 5) << 5) + (((lane >> 1) & 3) << 3) +
           (((lane >> 3) & 3) << 1) + (lane & 1);
  zn[(size_t)row * 64 + dw] = (unsigned int)all;
}

// ---- Kernel 2: symmetric Gram-GEMM (fp8), 256x128 lower-triangle tiles ----
// R19 champion + T5 s_setprio around the MFMA clusters (2 blocks/CU are at
// independent phases -> MFMA waves win arbitration vs staging waves).
__global__ __launch_bounds__(512, 4) void gemm_kernel(
    const unsigned char* __restrict__ zn, float* __restrict__ rowpartT,
    float* __restrict__ colpartT, float* __restrict__ pos) {
  __shared__ char As[TM * BK];  // 32 KiB, XOR-swizzled 16B groups
  __shared__ char Bs[TN * BK];  // 16 KiB

  const int t = threadIdx.x;
  // XCD-aware bijective swizzle (1056 = 8*132), then lower-tri decode
  int id = ((int)blockIdx.x & 7) * 132 + ((int)blockIdx.x >> 3);
  int bm = (int)((sqrtf((float)(4 * id + 1)) - 1.0f) * 0.5f);
  while (bm * (bm + 1) > id) --bm;
  while ((bm + 1) * (bm + 2) <= id) ++bm;
  const int bn = id - bm * (bm + 1);  // 0 .. 2*bm+1

  const int l = t & 63;
  const int w = t >> 6;   // 0..7
  const int wr = w >> 1;  // 0..3 : 64-row band
  const int wc = w & 1;   // 0..1 : 64-col band

  f32x4 acc[4][4];
  const f32x4 vzero = {0.f, 0.f, 0.f, 0.f};
#pragma unroll
  for (int mi = 0; mi < 4; ++mi)
#pragma unroll
    for (int ni = 0; ni < 4; ++ni) acc[mi][ni] = vzero;

  const char* zb = (const char*)zn;  // fp8 rows: 256 B
  const int rloc = t >> 3;                // 0..63 (row within 64-row round)
  const int gsrc = (t & 7) ^ (rloc & 7);  // pre-swizzled source 16B-group
  const char* aG = zb + (size_t)(bm * TM + rloc) * 256 + gsrc * 16;
  const char* bG = zb + (size_t)(bn * TN + rloc) * 256 + gsrc * 16;

  union F8 {
    i32x4 v;
    long h[2];
  };

#pragma unroll
  for (int kt = 0; kt < KK / BK; ++kt) {  // 2 iterations
    if (kt) __syncthreads();  // previous tile fully consumed
#pragma unroll
    for (int ro = 0; ro < 4; ++ro)  // A: 256 rows, 4 rounds of 64
      gload_lds16(aG + (size_t)ro * (64 * 256) + kt * 128,
                  (char*)As + ro * 8192 + t * 16);
#pragma unroll
    for (int ro = 0; ro < 2; ++ro)  // B: 128 rows, 2 rounds of 64
      gload_lds16(bG + (size_t)ro * (64 * 256) + kt * 128,
                  (char*)Bs + ro * 8192 + t * 16);
    asm volatile("s_waitcnt vmcnt(0)" ::: "memory");
    __syncthreads();

    // fragment loads: quarter q owns logical groups q*2 (kk=0,1) and
    // q*2+1 (kk=2,3); physical group = logical ^ (r&7).
    const int q2 = (l >> 4) << 1;
    F8 b01[4], b23[4];
#pragma unroll
    for (int ni = 0; ni < 4; ++ni) {
      int r = wc * 64 + ni * 16 + (l & 15);
      int s = r & 7;
      b01[ni].v = *(const i32x4*)(Bs + r * 128 + ((q2 ^ s) << 4));
      b23[ni].v = *(const i32x4*)(Bs + r * 128 + (((q2 + 1) ^ s) << 4));
    }
#pragma unroll
    for (int mi = 0; mi < 4; ++mi) {
      int r = wr * 64 + mi * 16 + (l & 15);
      int s = r & 7;
      F8 a01, a23;
      a01.v = *(const i32x4*)(As + r * 128 + ((q2 ^ s) << 4));
      a23.v = *(const i32x4*)(As + r * 128 + (((q2 + 1) ^ s) << 4));
      __builtin_amdgcn_s_setprio(1);
#pragma unroll
      for (int ni = 0; ni < 4; ++ni) {
        acc[mi][ni] = __builtin_amdgcn_mfma_f32_16x16x32_fp8_fp8(
            a01.h[0], b01[ni].h[0], acc[mi][ni], 0, 0, 0);
        acc[mi][ni] = __builtin_amdgcn_mfma_f32_16x16x32_fp8_fp8(
            a01.h[1], b01[ni].h[1], acc[mi][ni], 0, 0, 0);
        acc[mi][ni] = __builtin_amdgcn_mfma_f32_16x16x32_fp8_fp8(
            a23.h[0], b23[ni].h[0], acc[mi][ni], 0, 0, 0);
        acc[mi][ni] = __builtin_amdgcn_mfma_f32_16x16x32_fp8_fp8(
            a23.h[1], b23[ni].h[1], acc[mi][ni], 0, 0, 0);
      }
      __builtin_amdgcn_s_setprio(0);
    }
  }

  // ---- epilogue: p = exp(10s-10) for gc<gr only; private partial slots ----
  const int e16 = l >> 4;
  const int rowBase = bm * TM + wr * 64 + (e16 << 2);
  const int colBase = bn * TN + wc * 64 + (l & 15);
  const float C1 = 14.4269504088896340736f;  // 10*log2(e)
  float rs[4][4];
  float cs[4] = {0.f, 0.f, 0.f, 0.f};
#pragma unroll
  for (int mi = 0; mi < 4; ++mi) {
#pragma unroll
    for (int j = 0; j < 4; ++j) rs[mi][j] = 0.f;
#pragma unroll
    for (int ni = 0; ni < 4; ++ni) {
#pragma unroll
      for (int j = 0; j < 4; ++j) {
        int gr = rowBase + mi * 16 + j;
        int gc = colBase + ni * 16;
        float a = acc[mi][ni][j];
        if (gc == (gr ^ HN)) {  // strictly-lower hit: write both directions
          pos[gr] = a * 10.0f;
          pos[gc] = a * 10.0f;
        }
        float p = (gc < gr) ? exp2f(fmaf(a, C1, -C1)) : 0.0f;
        rs[mi][j] += p;
        cs[ni] += p;
      }
    }
  }
#pragma unroll
  for (int mi = 0; mi < 4; ++mi)
#pragma unroll
    for (int j = 0; j < 4; ++j) {
      float v = rs[mi][j];
      v += __shfl_xor(v, 1, 64);
      v += __shfl_xor(v, 2, 64);
      v += __shfl_xor(v, 4, 64);
      v += __shfl_xor(v, 8, 64);
      rs[mi][j] = v;  // valid in lanes with (l&15)==0
    }
#pragma unroll
  for (int ni = 0; ni < 4; ++ni) {
    float v = cs[ni];
    v += __shfl_xor(v, 16, 64);
    v += __shfl_xor(v, 32, 64);
    cs[ni] = v;  // valid in lanes l<16
  }
  // private-slot stores: one writer per slot element, no merge needed
  if ((l & 15) == 0) {
    float* dst = rowpartT + (size_t)(2 * bn + wc) * NN;  // 128 slots
#pragma unroll
    for (int mi = 0; mi < 4; ++mi) {
      float4 v4 = make_float4(rs[mi][0], rs[mi][1], rs[mi][2], rs[mi][3]);
      *(float4*)(dst + rowBase + mi * 16) = v4;
    }
  }
  if (l < 16) {
    float* dst = colpartT + (size_t)(4 * bm + wr) * NN;  // 128 slots
#pragma unroll
    for (int ni = 0; ni < 4; ++ni) dst[colBase + ni * 16] = cs[ni];
  }
}

// ---- Kernel 3: loss = mean(10 + ln(rowsum_i) - pos_i), 8 thr/row ----
__global__ void finalize_kernel(const float* __restrict__ rowpartT,
                                const float* __restrict__ colpartT,
                                const float* __restrict__ pos,
                                float* __restrict__ out) {
  const int tid = threadIdx.x;
  const int j = tid & 7;                       // sub-lane within row group
  const int i = blockIdx.x * 32 + (tid >> 3);  // row
  const int bm = i >> 8, cn = i >> 7;
  float sum = 0.f;
  // row slots: k in [0, 4bm+4)
  for (int k = j; k < 4 * bm + 4; k += 8) sum += rowpartT[(size_t)k * NN + i];
  // col slots: k in [4*(cn>>1), 128)
  for (int k = 4 * (cn >> 1) + j; k < 128; k += 8)
    sum += colpartT[(size_t)k * NN + i];
  // merge the 8 sub-lanes
  sum += __shfl_xor(sum, 1, 64);
  sum += __shfl_xor(sum, 2, 64);
  sum += __shfl_xor(sum, 4, 64);
  float acc = (j == 0) ? (10.0f + logf(sum) - pos[i]) : 0.0f;
  // sum the 8 rows of this wave (nonzero only in lanes with j==0)
  acc += __shfl_xor(acc, 8, 64);
  acc += __shfl_xor(acc, 16, 64);
  acc += __shfl_xor(acc, 32, 64);
  __shared__ float ws[4];
  if ((tid & 63) == 0) ws[tid >> 6] = acc;
  __syncthreads();
  if (tid == 0)
    atomicAdd(out, (ws[0] + ws[1] + ws[2] + ws[3]) * (1.0f / (float)NN));
}

extern "C" void kernel_launch(void* const* d_in, const int* in_sizes, int n_in,
                              void* d_out, int out_size, void* d_ws,
                              size_t ws_size, hipStream_t stream) {
  const float* z = (const float*)d_in[0];
  float* out = (float*)d_out;
  char* ws = (char*)d_ws;
  unsigned char* zn = (unsigned char*)ws;      // 2 MiB fp8
  float* rowpartT = (float*)(ws + (2 << 20));  // 4 MiB [128][8192]
  float* colpartT = (float*)(ws + (6 << 20));  // 4 MiB [128][8192]
  float* pos = (float*)(ws + (10 << 20));      // 32 KiB

  nrm_kernel<<<NN / 4, 256, 0, stream>>>(z, (unsigned int*)zn, out);
  gemm_kernel<<<NBLK, 512, 0, stream>>>(zn, rowpartT, colpartT, pos);
  finalize_kernel<<<NN / 32, 256, 0, stream>>>(rowpartT, colpartT, pos, out);
}

// Round 21
// 44.359 us; speedup vs baseline: 1.0317x; 1.0317x over previous
//
#include <hip/hip_runtime.h>
#include <hip/hip_bf16.h>

#define NN 8192
#define KK 256
#define HN 4096
#define TM 256
#define TN 128
#define BK 128  // fp8 bytes per LDS row (128 B rows = verified swizzle)
#define NBLK 1056  // lower-triangle 256x128 tiles: 8*132, bijective XCD swizzle

typedef __attribute__((ext_vector_type(4))) float f32x4;
typedef __attribute__((ext_vector_type(4))) int i32x4;

__device__ __forceinline__ void gload_lds16(const void* g, void* l) {
  __builtin_amdgcn_global_load_lds(
      (const __attribute__((address_space(1))) unsigned int*)g,
      (__attribute__((address_space(3))) unsigned int*)l, 16, 0, 0);
}

// ---- Kernel 1: row-normalize z (f32) -> fp8 e4m3 zn (K-PERMUTED layout);
// block 0 zeroes out. Within each 128-byte half-row (kt), original
// k = kk*32 + q*8 + j is stored at p = q*32 + kk*8 + j. Gram dot-products
// are invariant since both operands share the same K-permutation.
__global__ void nrm_kernel(const float* __restrict__ z,
                           unsigned int* __restrict__ zn,
                           float* __restrict__ out) {
  if (blockIdx.x == 0 && threadIdx.x == 0) out[0] = 0.0f;
  int row = (blockIdx.x << 2) + (threadIdx.x >> 6);
  int lane = threadIdx.x & 63;
  float4 v = ((const float4*)(z + (size_t)row * KK))[lane];
  float ss = v.x * v.x + v.y * v.y + v.z * v.z + v.w * v.w;
#pragma unroll
  for (int off = 32; off; off >>= 1) ss += __shfl_xor(ss, off, 64);
  float scale = 1.0f / fmaxf(sqrtf(ss), 1e-8f);
  int lo = __builtin_amdgcn_cvt_pk_fp8_f32(v.x * scale, v.y * scale, 0, false);
  int all = __builtin_amdgcn_cvt_pk_fp8_f32(v.z * scale, v.w * scale, lo, true);
  // lane covers k = 4*lane..+3. Bits: kt=b5, kk=(b4b3), q=(b2b1), half=b0.
  // permuted dword = kt*32 + q*8 + kk*2 + b0  (bit permutation: bijective)
  int dw = ((lane >> 5) << 5) + (((lane >> 1) & 3) << 3) +
           (((lane >> 3) & 3) << 1) + (lane & 1);
  zn[(size_t)row * 64 + dw] = (unsigned int)all;
}

// ---- Kernel 2: symmetric Gram-GEMM (fp8), 256x128 lower-triangle tiles ----
// Champion (R19): 512 thr / 8 waves of 64x64, single-buffer 48 KB LDS,
// BK=128 fp8 (2 K-steps), K-permuted layout -> ds_read_b128 fragment loads
// (0 bank conflicts), private-slot epilogue, no atomics.
__global__ __launch_bounds__(512, 4) void gemm_kernel(
    const unsigned char* __restrict__ zn, float* __restrict__ rowpartT,
    float* __restrict__ colpartT, float* __restrict__ pos) {
  __shared__ char As[TM * BK];  // 32 KiB, XOR-swizzled 16B groups
  __shared__ char Bs[TN * BK];  // 16 KiB

  const int t = threadIdx.x;
  // XCD-aware bijective swizzle (1056 = 8*132), then lower-tri decode
  int id = ((int)blockIdx.x & 7) * 132 + ((int)blockIdx.x >> 3);
  int bm = (int)((sqrtf((float)(4 * id + 1)) - 1.0f) * 0.5f);
  while (bm * (bm + 1) > id) --bm;
  while ((bm + 1) * (bm + 2) <= id) ++bm;
  const int bn = id - bm * (bm + 1);  // 0 .. 2*bm+1

  const int l = t & 63;
  const int w = t >> 6;   // 0..7
  const int wr = w >> 1;  // 0..3 : 64-row band
  const int wc = w & 1;   // 0..1 : 64-col band

  f32x4 acc[4][4];
  const f32x4 vzero = {0.f, 0.f, 0.f, 0.f};
#pragma unroll
  for (int mi = 0; mi < 4; ++mi)
#pragma unroll
    for (int ni = 0; ni < 4; ++ni) acc[mi][ni] = vzero;

  const char* zb = (const char*)zn;  // fp8 rows: 256 B
  const int rloc = t >> 3;                // 0..63 (row within 64-row round)
  const int gsrc = (t & 7) ^ (rloc & 7);  // pre-swizzled source 16B-group
  const char* aG = zb + (size_t)(bm * TM + rloc) * 256 + gsrc * 16;
  const char* bG = zb + (size_t)(bn * TN + rloc) * 256 + gsrc * 16;

  union F8 {
    i32x4 v;
    long h[2];
  };

#pragma unroll
  for (int kt = 0; kt < KK / BK; ++kt) {  // 2 iterations
    if (kt) __syncthreads();  // previous tile fully consumed
#pragma unroll
    for (int ro = 0; ro < 4; ++ro)  // A: 256 rows, 4 rounds of 64
      gload_lds16(aG + (size_t)ro * (64 * 256) + kt * 128,
                  (char*)As + ro * 8192 + t * 16);
#pragma unroll
    for (int ro = 0; ro < 2; ++ro)  // B: 128 rows, 2 rounds of 64
      gload_lds16(bG + (size_t)ro * (64 * 256) + kt * 128,
                  (char*)Bs + ro * 8192 + t * 16);
    asm volatile("s_waitcnt vmcnt(0)" ::: "memory");
    __syncthreads();

    // fragment loads: quarter q owns logical groups q*2 (kk=0,1) and
    // q*2+1 (kk=2,3); physical group = logical ^ (r&7).
    const int q2 = (l >> 4) << 1;
    F8 b01[4], b23[4];
#pragma unroll
    for (int ni = 0; ni < 4; ++ni) {
      int r = wc * 64 + ni * 16 + (l & 15);
      int s = r & 7;
      b01[ni].v = *(const i32x4*)(Bs + r * 128 + ((q2 ^ s) << 4));
      b23[ni].v = *(const i32x4*)(Bs + r * 128 + (((q2 + 1) ^ s) << 4));
    }
#pragma unroll
    for (int mi = 0; mi < 4; ++mi) {
      int r = wr * 64 + mi * 16 + (l & 15);
      int s = r & 7;
      F8 a01, a23;
      a01.v = *(const i32x4*)(As + r * 128 + ((q2 ^ s) << 4));
      a23.v = *(const i32x4*)(As + r * 128 + (((q2 + 1) ^ s) << 4));
#pragma unroll
      for (int ni = 0; ni < 4; ++ni) {
        acc[mi][ni] = __builtin_amdgcn_mfma_f32_16x16x32_fp8_fp8(
            a01.h[0], b01[ni].h[0], acc[mi][ni], 0, 0, 0);
        acc[mi][ni] = __builtin_amdgcn_mfma_f32_16x16x32_fp8_fp8(
            a01.h[1], b01[ni].h[1], acc[mi][ni], 0, 0, 0);
        acc[mi][ni] = __builtin_amdgcn_mfma_f32_16x16x32_fp8_fp8(
            a23.h[0], b23[ni].h[0], acc[mi][ni], 0, 0, 0);
        acc[mi][ni] = __builtin_amdgcn_mfma_f32_16x16x32_fp8_fp8(
            a23.h[1], b23[ni].h[1], acc[mi][ni], 0, 0, 0);
      }
    }
  }

  // ---- epilogue: p = exp(10s-10) for gc<gr only; private partial slots ----
  const int e16 = l >> 4;
  const int rowBase = bm * TM + wr * 64 + (e16 << 2);
  const int colBase = bn * TN + wc * 64 + (l & 15);
  const float C1 = 14.4269504088896340736f;  // 10*log2(e)
  float rs[4][4];
  float cs[4] = {0.f, 0.f, 0.f, 0.f};
#pragma unroll
  for (int mi = 0; mi < 4; ++mi) {
#pragma unroll
    for (int j = 0; j < 4; ++j) rs[mi][j] = 0.f;
#pragma unroll
    for (int ni = 0; ni < 4; ++ni) {
#pragma unroll
      for (int j = 0; j < 4; ++j) {
        int gr = rowBase + mi * 16 + j;
        int gc = colBase + ni * 16;
        float a = acc[mi][ni][j];
        if (gc == (gr ^ HN)) {  // strictly-lower hit: write both directions
          pos[gr] = a * 10.0f;
          pos[gc] = a * 10.0f;
        }
        float p = (gc < gr) ? exp2f(fmaf(a, C1, -C1)) : 0.0f;
        rs[mi][j] += p;
        cs[ni] += p;
      }
    }
  }
#pragma unroll
  for (int mi = 0; mi < 4; ++mi)
#pragma unroll
    for (int j = 0; j < 4; ++j) {
      float v = rs[mi][j];
      v += __shfl_xor(v, 1, 64);
      v += __shfl_xor(v, 2, 64);
      v += __shfl_xor(v, 4, 64);
      v += __shfl_xor(v, 8, 64);
      rs[mi][j] = v;  // valid in lanes with (l&15)==0
    }
#pragma unroll
  for (int ni = 0; ni < 4; ++ni) {
    float v = cs[ni];
    v += __shfl_xor(v, 16, 64);
    v += __shfl_xor(v, 32, 64);
    cs[ni] = v;  // valid in lanes l<16
  }
  // private-slot stores: one writer per slot element, no merge needed
  if ((l & 15) == 0) {
    float* dst = rowpartT + (size_t)(2 * bn + wc) * NN;  // 128 slots
#pragma unroll
    for (int mi = 0; mi < 4; ++mi) {
      float4 v4 = make_float4(rs[mi][0], rs[mi][1], rs[mi][2], rs[mi][3]);
      *(float4*)(dst + rowBase + mi * 16) = v4;
    }
  }
  if (l < 16) {
    float* dst = colpartT + (size_t)(4 * bm + wr) * NN;  // 128 slots
#pragma unroll
    for (int ni = 0; ni < 4; ++ni) dst[colBase + ni * 16] = cs[ni];
  }
}

// ---- Kernel 3: loss = mean(10 + ln(rowsum_i) - pos_i), 8 thr/row ----
__global__ void finalize_kernel(const float* __restrict__ rowpartT,
                                const float* __restrict__ colpartT,
                                const float* __restrict__ pos,
                                float* __restrict__ out) {
  const int tid = threadIdx.x;
  const int j = tid & 7;                       // sub-lane within row group
  const int i = blockIdx.x * 32 + (tid >> 3);  // row
  const int bm = i >> 8, cn = i >> 7;
  float sum = 0.f;
  // row slots: k in [0, 4bm+4)
  for (int k = j; k < 4 * bm + 4; k += 8) sum += rowpartT[(size_t)k * NN + i];
  // col slots: k in [4*(cn>>1), 128)
  for (int k = 4 * (cn >> 1) + j; k < 128; k += 8)
    sum += colpartT[(size_t)k * NN + i];
  // merge the 8 sub-lanes
  sum += __shfl_xor(sum, 1, 64);
  sum += __shfl_xor(sum, 2, 64);
  sum += __shfl_xor(sum, 4, 64);
  float acc = (j == 0) ? (10.0f + logf(sum) - pos[i]) : 0.0f;
  // sum the 8 rows of this wave (nonzero only in lanes with j==0)
  acc += __shfl_xor(acc, 8, 64);
  acc += __shfl_xor(acc, 16, 64);
  acc += __shfl_xor(acc, 32, 64);
  __shared__ float ws[4];
  if ((tid & 63) == 0) ws[tid >> 6] = acc;
  __syncthreads();
  if (tid == 0)
    atomicAdd(out, (ws[0] + ws[1] + ws[2] + ws[3]) * (1.0f / (float)NN));
}

extern "C" void kernel_launch(void* const* d_in, const int* in_sizes, int n_in,
                              void* d_out, int out_size, void* d_ws,
                              size_t ws_size, hipStream_t stream) {
  const float* z = (const float*)d_in[0];
  float* out = (float*)d_out;
  char* ws = (char*)d_ws;
  unsigned char* zn = (unsigned char*)ws;      // 2 MiB fp8
  float* rowpartT = (float*)(ws + (2 << 20));  // 4 MiB [128][8192]
  float* colpartT = (float*)(ws + (6 << 20));  // 4 MiB [128][8192]
  float* pos = (float*)(ws + (10 << 20));      // 32 KiB

  nrm_kernel<<<NN / 4, 256, 0, stream>>>(z, (unsigned int*)zn, out);
  gemm_kernel<<<NBLK, 512, 0, stream>>>(zn, rowpartT, colpartT, pos);
  finalize_kernel<<<NN / 32, 256, 0, stream>>>(rowpartT, colpartT, pos, out);
}